// Round 1
// baseline (507.286 us; speedup 1.0000x reference)
//
#include <hip/hip_runtime.h>
#include <math.h>

#define NPTS 35937        // 33^3
#define HID 256
#define HSTRIDE 260       // 256 + 4: keeps float4 alignment (260*4B = 1040 = 65*16)
#define TPB 256

__device__ __forceinline__ float fast_tanh(float x) {
    float e = __expf(2.0f * x);                 // overflow -> inf -> returns 1; underflow -> 0 -> returns -1
    return 1.0f - __fdividef(2.0f, e + 1.0f);
}

__device__ __forceinline__ void dense_tanh_layer(
    const float* __restrict__ W, const float* __restrict__ bias,
    float (*hbuf)[HSTRIDE], int r0, int jt)
{
    float acc[16][4];
    float4 bb = *(const float4*)(bias + jt);
    #pragma unroll
    for (int rr = 0; rr < 16; ++rr) {
        acc[rr][0] = bb.x; acc[rr][1] = bb.y; acc[rr][2] = bb.z; acc[rr][3] = bb.w;
    }
    for (int k = 0; k < HID; k += 4) {
        float4 wa = *(const float4*)(W + (k + 0) * HID + jt);
        float4 wb = *(const float4*)(W + (k + 1) * HID + jt);
        float4 wc = *(const float4*)(W + (k + 2) * HID + jt);
        float4 wd = *(const float4*)(W + (k + 3) * HID + jt);
        #pragma unroll
        for (int rr = 0; rr < 16; ++rr) {
            float4 h = *(const float4*)&hbuf[r0 + rr][k];
            acc[rr][0] = fmaf(h.x, wa.x, acc[rr][0]);
            acc[rr][1] = fmaf(h.x, wa.y, acc[rr][1]);
            acc[rr][2] = fmaf(h.x, wa.z, acc[rr][2]);
            acc[rr][3] = fmaf(h.x, wa.w, acc[rr][3]);
            acc[rr][0] = fmaf(h.y, wb.x, acc[rr][0]);
            acc[rr][1] = fmaf(h.y, wb.y, acc[rr][1]);
            acc[rr][2] = fmaf(h.y, wb.z, acc[rr][2]);
            acc[rr][3] = fmaf(h.y, wb.w, acc[rr][3]);
            acc[rr][0] = fmaf(h.z, wc.x, acc[rr][0]);
            acc[rr][1] = fmaf(h.z, wc.y, acc[rr][1]);
            acc[rr][2] = fmaf(h.z, wc.z, acc[rr][2]);
            acc[rr][3] = fmaf(h.z, wc.w, acc[rr][3]);
            acc[rr][0] = fmaf(h.w, wd.x, acc[rr][0]);
            acc[rr][1] = fmaf(h.w, wd.y, acc[rr][1]);
            acc[rr][2] = fmaf(h.w, wd.z, acc[rr][2]);
            acc[rr][3] = fmaf(h.w, wd.w, acc[rr][3]);
        }
    }
    __syncthreads();   // all reads of hbuf done before overwrite
    #pragma unroll
    for (int rr = 0; rr < 16; ++rr) {
        float4 o;
        o.x = fast_tanh(acc[rr][0]);
        o.y = fast_tanh(acc[rr][1]);
        o.z = fast_tanh(acc[rr][2]);
        o.w = fast_tanh(acc[rr][3]);
        *(float4*)&hbuf[r0 + rr][jt] = o;
    }
    __syncthreads();
}

// One block: 32 grid points x 2 variants = 64 rows through the whole MLP.
__global__ __launch_bounds__(256) void nilut_lut_kernel(
    const float* __restrict__ param,
    const float* __restrict__ W0, const float* __restrict__ b0,
    const float* __restrict__ W1, const float* __restrict__ b1,
    const float* __restrict__ W2, const float* __restrict__ b2,
    const float* __restrict__ W3, const float* __restrict__ b3,
    const float* __restrict__ W4, const float* __restrict__ b4,
    float* __restrict__ lut4)
{
    __shared__ float hbuf[64][HSTRIDE];
    __shared__ float ibuf[64][12];
    __shared__ float w4buf[HID][4];
    __shared__ float b4buf[4];
    __shared__ float obuf[64][4];

    const int t = threadIdx.x;
    const int pblock = blockIdx.x * 32;   // first grid-point of this block

    // stage W4 (256x3) padded to [256][4]
    for (int idx = t; idx < HID * 4; idx += TPB) {
        int k = idx >> 2, c = idx & 3;
        w4buf[k][c] = (c < 3) ? W4[k * 3 + c] : 0.0f;
    }
    if (t < 4) b4buf[t] = (t < 3) ? b4[t] : 0.0f;

    // build 64 input rows: row m -> point pblock + m/2, variant m&1 (1 = params zeroed)
    if (t < 64) {
        int pn = pblock + (t >> 1);
        if (pn >= NPTS) pn = NPTS - 1;
        int v = t & 1;
        int ii = pn / 1089;
        int rem = pn - ii * 1089;
        int jj = rem / 33;
        int kk = rem - jj * 33;
        float r = kk * (1.0f / 32.0f);
        float g = jj * (1.0f / 32.0f);
        float b = ii * (1.0f / 32.0f);
        float lo = fminf(r, fminf(g, b));
        float hi = fmaxf(r, fmaxf(g, b));
        float mid = r + g + b - lo - hi;    // exact: multiples of 1/32
        ibuf[t][0] = r; ibuf[t][1] = g; ibuf[t][2] = b;
        ibuf[t][3] = (v == 0) ? param[0] : 0.0f;
        ibuf[t][4] = (v == 0) ? param[1] : 0.0f;
        ibuf[t][5] = (v == 0) ? param[2] : 0.0f;
        ibuf[t][6] = (v == 0) ? param[3] : 0.0f;
        ibuf[t][7] = (v == 0) ? param[4] : 0.0f;
        ibuf[t][8] = lo; ibuf[t][9] = mid; ibuf[t][10] = hi;
        ibuf[t][11] = 0.0f;
    }
    __syncthreads();

    const int jt = (t & 63) * 4;   // 4 contiguous output columns per thread
    const int r0 = (t >> 6) * 16;  // 16 rows per thread (wave-uniform)

    // ---- layer 0: 11 -> 256, relu ----
    {
        float acc[16][4];
        float4 bb = *(const float4*)(b0 + jt);
        #pragma unroll
        for (int rr = 0; rr < 16; ++rr) {
            acc[rr][0] = bb.x; acc[rr][1] = bb.y; acc[rr][2] = bb.z; acc[rr][3] = bb.w;
        }
        for (int k = 0; k < 11; ++k) {
            float4 w = *(const float4*)(W0 + k * HID + jt);
            #pragma unroll
            for (int rr = 0; rr < 16; ++rr) {
                float h = ibuf[r0 + rr][k];
                acc[rr][0] = fmaf(h, w.x, acc[rr][0]);
                acc[rr][1] = fmaf(h, w.y, acc[rr][1]);
                acc[rr][2] = fmaf(h, w.z, acc[rr][2]);
                acc[rr][3] = fmaf(h, w.w, acc[rr][3]);
            }
        }
        #pragma unroll
        for (int rr = 0; rr < 16; ++rr) {
            float4 o;
            o.x = fmaxf(acc[rr][0], 0.0f);
            o.y = fmaxf(acc[rr][1], 0.0f);
            o.z = fmaxf(acc[rr][2], 0.0f);
            o.w = fmaxf(acc[rr][3], 0.0f);
            *(float4*)&hbuf[r0 + rr][jt] = o;
        }
    }
    __syncthreads();

    // ---- layers 1..3: 256 -> 256, tanh ----
    dense_tanh_layer(W1, b1, hbuf, r0, jt);
    dense_tanh_layer(W2, b2, hbuf, r0, jt);
    dense_tanh_layer(W3, b3, hbuf, r0, jt);

    // ---- layer 4: 256 -> 3 (padded to 4) ----
    {
        int rr = t >> 2, c = t & 3;
        float a = b4buf[c];
        for (int k = 0; k < HID; k += 4) {
            float4 h = *(const float4*)&hbuf[rr][k];
            a = fmaf(h.x, w4buf[k + 0][c], a);
            a = fmaf(h.y, w4buf[k + 1][c], a);
            a = fmaf(h.z, w4buf[k + 2][c], a);
            a = fmaf(h.w, w4buf[k + 3][c], a);
        }
        obuf[rr][c] = a;
    }
    __syncthreads();

    // out[n][c] = net(inp) - net(zero_inp) + identity rgb
    if (t < 96) {
        int pl = t / 3, c = t - pl * 3;
        int n = pblock + pl;
        if (n < NPTS) {
            int ii = n / 1089;
            int rem = n - ii * 1089;
            int jj = rem / 33;
            int kk = rem - jj * 33;
            float rgb = (c == 0) ? kk * (1.0f / 32.0f)
                      : (c == 1) ? jj * (1.0f / 32.0f)
                                 : ii * (1.0f / 32.0f);
            lut4[n * 4 + c] = obuf[2 * pl][c] - obuf[2 * pl + 1][c] + rgb;
        }
    }
}

#define LERP(a, b, f) fmaf((f), (b) - (a), (a))

__global__ __launch_bounds__(256) void apply_lut_kernel(
    const float* __restrict__ img, const float* __restrict__ lut4,
    float* __restrict__ out)
{
    const int NP = 2160 * 3840;
    int idx = blockIdx.x * blockDim.x + threadIdx.x;
    int p = idx * 4;
    if (p >= NP) return;

    float4 rv = *(const float4*)(img + p);
    float4 gv = *(const float4*)(img + NP + p);
    float4 bv = *(const float4*)(img + 2 * NP + p);
    const float4* L = (const float4*)lut4;

    float rr[4] = {rv.x, rv.y, rv.z, rv.w};
    float gg[4] = {gv.x, gv.y, gv.z, gv.w};
    float bb[4] = {bv.x, bv.y, bv.z, bv.w};
    float ox[4], oy[4], oz[4];

    #pragma unroll
    for (int u = 0; u < 4; ++u) {
        float sr = rr[u] * 32.0f, sg = gg[u] * 32.0f, sb = bb[u] * 32.0f;
        float fir = fminf(fmaxf(floorf(sr), 0.0f), 31.0f);
        float fig = fminf(fmaxf(floorf(sg), 0.0f), 31.0f);
        float fib = fminf(fmaxf(floorf(sb), 0.0f), 31.0f);
        float fr = sr - fir, fg = sg - fig, fb = sb - fib;
        int ir = (int)fir, ig = (int)fig, ib = (int)fib;
        int base = ib * 1089 + ig * 33 + ir;

        float4 c000 = L[base],        c001 = L[base + 1];
        float4 c010 = L[base + 33],   c011 = L[base + 34];
        float4 c100 = L[base + 1089], c101 = L[base + 1090];
        float4 c110 = L[base + 1122], c111 = L[base + 1123];

        // lerp r, then g, then b — per output channel
        float x00 = LERP(c000.x, c001.x, fr), x01 = LERP(c010.x, c011.x, fr);
        float x10 = LERP(c100.x, c101.x, fr), x11 = LERP(c110.x, c111.x, fr);
        float x0 = LERP(x00, x01, fg), x1 = LERP(x10, x11, fg);
        ox[u] = LERP(x0, x1, fb);

        float y00 = LERP(c000.y, c001.y, fr), y01 = LERP(c010.y, c011.y, fr);
        float y10 = LERP(c100.y, c101.y, fr), y11 = LERP(c110.y, c111.y, fr);
        float y0 = LERP(y00, y01, fg), y1 = LERP(y10, y11, fg);
        oy[u] = LERP(y0, y1, fb);

        float z00 = LERP(c000.z, c001.z, fr), z01 = LERP(c010.z, c011.z, fr);
        float z10 = LERP(c100.z, c101.z, fr), z11 = LERP(c110.z, c111.z, fr);
        float z0 = LERP(z00, z01, fg), z1 = LERP(z10, z11, fg);
        oz[u] = LERP(z0, z1, fb);
    }

    *(float4*)(out + p)          = make_float4(ox[0], ox[1], ox[2], ox[3]);
    *(float4*)(out + NP + p)     = make_float4(oy[0], oy[1], oy[2], oy[3]);
    *(float4*)(out + 2 * NP + p) = make_float4(oz[0], oz[1], oz[2], oz[3]);
}

extern "C" void kernel_launch(void* const* d_in, const int* in_sizes, int n_in,
                              void* d_out, int out_size, void* d_ws, size_t ws_size,
                              hipStream_t stream) {
    const float* img   = (const float*)d_in[0];
    const float* param = (const float*)d_in[1];
    const float* W0 = (const float*)d_in[2];
    const float* b0 = (const float*)d_in[3];
    const float* W1 = (const float*)d_in[4];
    const float* b1 = (const float*)d_in[5];
    const float* W2 = (const float*)d_in[6];
    const float* b2 = (const float*)d_in[7];
    const float* W3 = (const float*)d_in[8];
    const float* b3 = (const float*)d_in[9];
    const float* W4 = (const float*)d_in[10];
    const float* b4 = (const float*)d_in[11];

    float* lut4 = (float*)d_ws;            // NPTS * 4 floats = 575 KB
    float* out  = (float*)d_out;

    int lut_blocks = (NPTS + 31) / 32;     // 1124
    hipLaunchKernelGGL(nilut_lut_kernel, dim3(lut_blocks), dim3(TPB), 0, stream,
                       param, W0, b0, W1, b1, W2, b2, W3, b3, W4, b4, lut4);

    const int NP = 2160 * 3840;
    int apply_blocks = (NP / 4 + TPB - 1) / TPB;   // 8100
    hipLaunchKernelGGL(apply_lut_kernel, dim3(apply_blocks), dim3(TPB), 0, stream,
                       img, lut4, out);
}

// Round 2
// 223.256 us; speedup vs baseline: 2.2722x; 2.2722x over previous
//
#include <hip/hip_runtime.h>
#include <math.h>

#define NPTS 35937        // 33^3
#define HID 256
#define TPB 256

typedef __attribute__((ext_vector_type(8))) short short8;
typedef __attribute__((ext_vector_type(4))) float f32x4;

// ---------- helpers ----------
__device__ __forceinline__ float fast_tanh(float x) {
    float e = __expf(2.0f * x);
    return 1.0f - __fdividef(2.0f, e + 1.0f);
}

__device__ __forceinline__ short f2bf(float f) {   // RNE float->bf16
    union { float f; unsigned u; } v; v.f = f;
    unsigned r = (v.u + 0x7fffu + ((v.u >> 16) & 1u)) >> 16;
    return (short)r;
}

// ---------- weight packing: bf16 MFMA B-fragment layout ----------
// Wp[frag f = tile*64+lane][j] = W[kt*32 + (lane>>4)*8 + j][nt*16 + (lane&15)]
// tile = kt*NT + nt.  Segments (in shorts):
//   W0p [0, 8192)        kt:1(K=32, k>=11 zero), nt:16
//   W1p [8192, 73728)    kt:8, nt:16
//   W2p [73728, 139264)
//   W3p [139264, 204800)
//   W4p [204800, 208896) kt:8, nt:1 (n>=3 zero)
#define W1P_OFF 8192
#define W2P_OFF 73728
#define W3P_OFF 139264
#define W4P_OFF 204800
#define WP_TOTAL 208896           // shorts -> 417792 bytes
#define LUT_BYTE_OFF 417792       // 16B aligned

__global__ __launch_bounds__(256) void pack_weights_kernel(
    const float* __restrict__ W0, const float* __restrict__ W1,
    const float* __restrict__ W2, const float* __restrict__ W3,
    const float* __restrict__ W4, short* __restrict__ P)
{
    int id = blockIdx.x * 256 + threadIdx.x;
    if (id >= 26112) return;
    const float* W; int f, NT, KREAL, NROW; long pbase;
    if (id < 1024)       { W = W0; f = id;         NT = 16; KREAL = 11;  NROW = 256; pbase = 0; }
    else if (id < 9216)  { W = W1; f = id - 1024;  NT = 16; KREAL = 256; NROW = 256; pbase = W1P_OFF; }
    else if (id < 17408) { W = W2; f = id - 9216;  NT = 16; KREAL = 256; NROW = 256; pbase = W2P_OFF; }
    else if (id < 25600) { W = W3; f = id - 17408; NT = 16; KREAL = 256; NROW = 256; pbase = W3P_OFF; }
    else                 { W = W4; f = id - 25600; NT = 1;  KREAL = 256; NROW = 3;   pbase = W4P_OFF; }
    int lane = f & 63;
    int tile = f >> 6;
    int nt = tile % NT, kt = tile / NT;
    int n  = nt * 16 + (lane & 15);
    int k0 = kt * 32 + ((lane >> 4) & 3) * 8;
    short v[8];
    #pragma unroll
    for (int j = 0; j < 8; ++j) {
        int k = k0 + j;
        float x = (k < KREAL && n < NROW) ? W[k * NROW + n] : 0.0f;
        v[j] = f2bf(x);
    }
    *(short8*)(P + pbase + (long)f * 8) = *(short8*)v;
}

// ---------- fused MLP via MFMA: 64 rows/block (32 points x 2 variants) ----------
#define HSTR 264   // bf16 row stride: 528 B -> row-lanes spread over 8 disjoint bank-quads

__global__ __launch_bounds__(256) void nilut_mfma_kernel(
    const float* __restrict__ param, const short* __restrict__ P,
    const float* __restrict__ b0, const float* __restrict__ b1,
    const float* __restrict__ b2, const float* __restrict__ b3,
    const float* __restrict__ b4, float* __restrict__ lut4)
{
    __shared__ short Hs[64][HSTR];   // hidden activations, bf16
    __shared__ short Is[64][40];     // layer-0 input rows (K padded to 32)
    __shared__ float OB[64][4];      // layer-4 outputs

    const int t = threadIdx.x;
    const int pblock = blockIdx.x * 32;
    const int lane = t & 63;
    const int wid  = t >> 6;        // 0..3
    const int lr = lane & 15;
    const int hi = lane >> 4;       // 0..3
    const int k8 = hi * 8;

    // build 64 input rows: row m -> point pblock + m/2, variant m&1 (1 = params zeroed)
    if (t < 64) {
        int pn = pblock + (t >> 1);
        if (pn >= NPTS) pn = NPTS - 1;
        int v = t & 1;
        int ii = pn / 1089;
        int rem = pn - ii * 1089;
        int jj = rem / 33;
        int kk = rem - jj * 33;
        float r = kk * (1.0f / 32.0f);
        float g = jj * (1.0f / 32.0f);
        float b = ii * (1.0f / 32.0f);
        float lo = fminf(r, fminf(g, b));
        float hv = fmaxf(r, fmaxf(g, b));
        float mid = r + g + b - lo - hv;    // exact: multiples of 1/32
        Is[t][0] = f2bf(r); Is[t][1] = f2bf(g); Is[t][2] = f2bf(b);
        #pragma unroll
        for (int q = 0; q < 5; ++q)
            Is[t][3 + q] = (v == 0) ? f2bf(param[q]) : (short)0;
        Is[t][8] = f2bf(lo); Is[t][9] = f2bf(mid); Is[t][10] = f2bf(hv);
        #pragma unroll
        for (int q = 11; q < 40; ++q) Is[t][q] = (short)0;
    }
    __syncthreads();

    f32x4 acc[4][4];

    // ---- layer 0: (K=32 padded) -> 256, relu ----
    {
        #pragma unroll
        for (int c = 0; c < 4; ++c) {
            float bv = b0[wid * 64 + c * 16 + lr];
            f32x4 in = {bv, bv, bv, bv};
            #pragma unroll
            for (int rt = 0; rt < 4; ++rt) acc[rt][c] = in;
        }
        short8 a[4], bfr[4];
        #pragma unroll
        for (int rt = 0; rt < 4; ++rt) a[rt] = *(const short8*)&Is[rt * 16 + lr][k8];
        #pragma unroll
        for (int c = 0; c < 4; ++c)
            bfr[c] = *(const short8*)(P + ((long)(wid * 4 + c) * 64 + lane) * 8);
        #pragma unroll
        for (int rt = 0; rt < 4; ++rt)
            #pragma unroll
            for (int c = 0; c < 4; ++c)
                acc[rt][c] = __builtin_amdgcn_mfma_f32_16x16x32_bf16(a[rt], bfr[c], acc[rt][c], 0, 0, 0);
        #pragma unroll
        for (int rt = 0; rt < 4; ++rt)
            #pragma unroll
            for (int c = 0; c < 4; ++c)
                #pragma unroll
                for (int q = 0; q < 4; ++q)
                    Hs[rt * 16 + hi * 4 + q][wid * 64 + c * 16 + lr] = f2bf(fmaxf(acc[rt][c][q], 0.0f));
    }
    __syncthreads();

    // ---- layers 1..3: 256 -> 256, tanh ----
    const long loff[3] = {W1P_OFF, W2P_OFF, W3P_OFF};
    const float* bptr[3];
    bptr[0] = b1; bptr[1] = b2; bptr[2] = b3;
    for (int L = 0; L < 3; ++L) {
        const short* WL = P + loff[L];
        const float* bb = bptr[L];
        #pragma unroll
        for (int c = 0; c < 4; ++c) {
            float bv = bb[wid * 64 + c * 16 + lr];
            f32x4 in = {bv, bv, bv, bv};
            #pragma unroll
            for (int rt = 0; rt < 4; ++rt) acc[rt][c] = in;
        }
        #pragma unroll
        for (int kt = 0; kt < 8; ++kt) {
            short8 a[4], bfr[4];
            #pragma unroll
            for (int rt = 0; rt < 4; ++rt)
                a[rt] = *(const short8*)&Hs[rt * 16 + lr][kt * 32 + k8];
            #pragma unroll
            for (int c = 0; c < 4; ++c)
                bfr[c] = *(const short8*)(WL + ((long)(kt * 16 + wid * 4 + c) * 64 + lane) * 8);
            #pragma unroll
            for (int rt = 0; rt < 4; ++rt)
                #pragma unroll
                for (int c = 0; c < 4; ++c)
                    acc[rt][c] = __builtin_amdgcn_mfma_f32_16x16x32_bf16(a[rt], bfr[c], acc[rt][c], 0, 0, 0);
        }
        __syncthreads();   // all reads of Hs done before overwrite
        #pragma unroll
        for (int rt = 0; rt < 4; ++rt)
            #pragma unroll
            for (int c = 0; c < 4; ++c)
                #pragma unroll
                for (int q = 0; q < 4; ++q)
                    Hs[rt * 16 + hi * 4 + q][wid * 64 + c * 16 + lr] = f2bf(fast_tanh(acc[rt][c][q]));
        __syncthreads();
    }

    // ---- layer 4: 256 -> 3 (N padded to 16); wave wid owns row-tile wid ----
    {
        float bv = (lr < 3) ? b4[lr] : 0.0f;
        f32x4 a4 = {bv, bv, bv, bv};
        const short* WL = P + W4P_OFF;
        #pragma unroll
        for (int kt = 0; kt < 8; ++kt) {
            short8 a = *(const short8*)&Hs[wid * 16 + lr][kt * 32 + k8];
            short8 b = *(const short8*)(WL + ((long)kt * 64 + lane) * 8);
            a4 = __builtin_amdgcn_mfma_f32_16x16x32_bf16(a, b, a4, 0, 0, 0);
        }
        if (lr < 3) {
            #pragma unroll
            for (int q = 0; q < 4; ++q)
                OB[wid * 16 + hi * 4 + q][lr] = a4[q];
        }
    }
    __syncthreads();

    // out[n][c] = net(inp) - net(zero_inp) + identity rgb
    if (t < 96) {
        int pl = t / 3, c = t - pl * 3;
        int n = pblock + pl;
        if (n < NPTS) {
            int ii = n / 1089;
            int rem = n - ii * 1089;
            int jj = rem / 33;
            int kk = rem - jj * 33;
            float rgb = (c == 0) ? kk * (1.0f / 32.0f)
                      : (c == 1) ? jj * (1.0f / 32.0f)
                                 : ii * (1.0f / 32.0f);
            lut4[n * 4 + c] = OB[2 * pl][c] - OB[2 * pl + 1][c] + rgb;
        }
    }
}

// ---------- trilinear apply ----------
#define LERP(a, b, f) fmaf((f), (b) - (a), (a))

__global__ __launch_bounds__(256) void apply_lut_kernel(
    const float* __restrict__ img, const float* __restrict__ lut4,
    float* __restrict__ out)
{
    const int NP = 2160 * 3840;
    int idx = blockIdx.x * blockDim.x + threadIdx.x;
    int p = idx * 4;
    if (p >= NP) return;

    float4 rv = *(const float4*)(img + p);
    float4 gv = *(const float4*)(img + NP + p);
    float4 bv = *(const float4*)(img + 2 * NP + p);
    const float4* L = (const float4*)lut4;

    float rr[4] = {rv.x, rv.y, rv.z, rv.w};
    float gg[4] = {gv.x, gv.y, gv.z, gv.w};
    float bb[4] = {bv.x, bv.y, bv.z, bv.w};
    float ox[4], oy[4], oz[4];

    #pragma unroll
    for (int u = 0; u < 4; ++u) {
        float sr = rr[u] * 32.0f, sg = gg[u] * 32.0f, sb = bb[u] * 32.0f;
        float fir = fminf(fmaxf(floorf(sr), 0.0f), 31.0f);
        float fig = fminf(fmaxf(floorf(sg), 0.0f), 31.0f);
        float fib = fminf(fmaxf(floorf(sb), 0.0f), 31.0f);
        float fr = sr - fir, fg = sg - fig, fb = sb - fib;
        int ir = (int)fir, ig = (int)fig, ib = (int)fib;
        int base = ib * 1089 + ig * 33 + ir;

        float4 c000 = L[base],        c001 = L[base + 1];
        float4 c010 = L[base + 33],   c011 = L[base + 34];
        float4 c100 = L[base + 1089], c101 = L[base + 1090];
        float4 c110 = L[base + 1122], c111 = L[base + 1123];

        float x00 = LERP(c000.x, c001.x, fr), x01 = LERP(c010.x, c011.x, fr);
        float x10 = LERP(c100.x, c101.x, fr), x11 = LERP(c110.x, c111.x, fr);
        float x0 = LERP(x00, x01, fg), x1 = LERP(x10, x11, fg);
        ox[u] = LERP(x0, x1, fb);

        float y00 = LERP(c000.y, c001.y, fr), y01 = LERP(c010.y, c011.y, fr);
        float y10 = LERP(c100.y, c101.y, fr), y11 = LERP(c110.y, c111.y, fr);
        float y0 = LERP(y00, y01, fg), y1 = LERP(y10, y11, fg);
        oy[u] = LERP(y0, y1, fb);

        float z00 = LERP(c000.z, c001.z, fr), z01 = LERP(c010.z, c011.z, fr);
        float z10 = LERP(c100.z, c101.z, fr), z11 = LERP(c110.z, c111.z, fr);
        float z0 = LERP(z00, z01, fg), z1 = LERP(z10, z11, fg);
        oz[u] = LERP(z0, z1, fb);
    }

    *(float4*)(out + p)          = make_float4(ox[0], ox[1], ox[2], ox[3]);
    *(float4*)(out + NP + p)     = make_float4(oy[0], oy[1], oy[2], oy[3]);
    *(float4*)(out + 2 * NP + p) = make_float4(oz[0], oz[1], oz[2], oz[3]);
}

extern "C" void kernel_launch(void* const* d_in, const int* in_sizes, int n_in,
                              void* d_out, int out_size, void* d_ws, size_t ws_size,
                              hipStream_t stream) {
    const float* img   = (const float*)d_in[0];
    const float* param = (const float*)d_in[1];
    const float* W0 = (const float*)d_in[2];
    const float* b0 = (const float*)d_in[3];
    const float* W1 = (const float*)d_in[4];
    const float* b1 = (const float*)d_in[5];
    const float* W2 = (const float*)d_in[6];
    const float* b2 = (const float*)d_in[7];
    const float* W3 = (const float*)d_in[8];
    const float* b3 = (const float*)d_in[9];
    const float* W4 = (const float*)d_in[10];
    const float* b4 = (const float*)d_in[11];

    short* P    = (short*)d_ws;                               // 417792 B
    float* lut4 = (float*)((char*)d_ws + LUT_BYTE_OFF);       // 574992 B
    float* out  = (float*)d_out;

    hipLaunchKernelGGL(pack_weights_kernel, dim3(102), dim3(TPB), 0, stream,
                       W0, W1, W2, W3, W4, P);

    int lut_blocks = (NPTS + 31) / 32;     // 1124
    hipLaunchKernelGGL(nilut_mfma_kernel, dim3(lut_blocks), dim3(TPB), 0, stream,
                       param, P, b0, b1, b2, b3, b4, lut4);

    const int NP = 2160 * 3840;
    int apply_blocks = (NP / 4 + TPB - 1) / TPB;   // 8100
    hipLaunchKernelGGL(apply_lut_kernel, dim3(apply_blocks), dim3(TPB), 0, stream,
                       img, lut4, out);
}

// Round 3
// 142.257 us; speedup vs baseline: 3.5660x; 1.5694x over previous
//
#include <hip/hip_runtime.h>
#include <hip/hip_fp16.h>
#include <math.h>

#define NPTS 35937        // 33^3
#define HID 256
#define TPB 256

typedef __attribute__((ext_vector_type(8))) short short8;
typedef __attribute__((ext_vector_type(4))) float f32x4;

// ---------- helpers ----------
__device__ __forceinline__ float fast_tanh(float x) {
    float e = __expf(2.0f * x);
    return 1.0f - __fdividef(2.0f, e + 1.0f);
}

__device__ __forceinline__ short f2bf(float f) {   // RNE float->bf16
    union { float f; unsigned u; } v; v.f = f;
    unsigned r = (v.u + 0x7fffu + ((v.u >> 16) & 1u)) >> 16;
    return (short)r;
}

// ---------- workspace layout ----------
// P        [0, 417792)          bf16 packed weights
// lut4     [417792, 992784)     fp32x4 LUT (35937 * 16 B)
// cells    [992896, 3090048)    fp16x4 duplicated-corner cells: 32^3 * 64 B
#define W1P_OFF 8192
#define W2P_OFF 73728
#define W3P_OFF 139264
#define W4P_OFF 204800
#define LUT_BYTE_OFF 417792
#define CELL_BYTE_OFF 992896      // 64B aligned

__global__ __launch_bounds__(256) void pack_weights_kernel(
    const float* __restrict__ W0, const float* __restrict__ W1,
    const float* __restrict__ W2, const float* __restrict__ W3,
    const float* __restrict__ W4, short* __restrict__ P)
{
    int id = blockIdx.x * 256 + threadIdx.x;
    if (id >= 26112) return;
    const float* W; int f, NT, KREAL, NROW; long pbase;
    if (id < 1024)       { W = W0; f = id;         NT = 16; KREAL = 11;  NROW = 256; pbase = 0; }
    else if (id < 9216)  { W = W1; f = id - 1024;  NT = 16; KREAL = 256; NROW = 256; pbase = W1P_OFF; }
    else if (id < 17408) { W = W2; f = id - 9216;  NT = 16; KREAL = 256; NROW = 256; pbase = W2P_OFF; }
    else if (id < 25600) { W = W3; f = id - 17408; NT = 16; KREAL = 256; NROW = 256; pbase = W3P_OFF; }
    else                 { W = W4; f = id - 25600; NT = 1;  KREAL = 256; NROW = 3;   pbase = W4P_OFF; }
    int lane = f & 63;
    int tile = f >> 6;
    int nt = tile % NT, kt = tile / NT;
    int n  = nt * 16 + (lane & 15);
    int k0 = kt * 32 + ((lane >> 4) & 3) * 8;
    short v[8];
    #pragma unroll
    for (int j = 0; j < 8; ++j) {
        int k = k0 + j;
        float x = (k < KREAL && n < NROW) ? W[k * NROW + n] : 0.0f;
        v[j] = f2bf(x);
    }
    *(short8*)(P + pbase + (long)f * 8) = *(short8*)v;
}

// ---------- fused MLP via MFMA: 64 rows/block (32 points x 2 variants) ----------
#define HSTR 264   // bf16 row stride: 528 B -> row-lanes spread over 8 disjoint bank-quads

__global__ __launch_bounds__(256) void nilut_mfma_kernel(
    const float* __restrict__ param, const short* __restrict__ P,
    const float* __restrict__ b0, const float* __restrict__ b1,
    const float* __restrict__ b2, const float* __restrict__ b3,
    const float* __restrict__ b4, float* __restrict__ lut4)
{
    __shared__ short Hs[64][HSTR];   // hidden activations, bf16
    __shared__ short Is[64][40];     // layer-0 input rows (K padded to 32)
    __shared__ float OB[64][4];      // layer-4 outputs

    const int t = threadIdx.x;
    const int pblock = blockIdx.x * 32;
    const int lane = t & 63;
    const int wid  = t >> 6;        // 0..3
    const int lr = lane & 15;
    const int hi = lane >> 4;       // 0..3
    const int k8 = hi * 8;

    if (t < 64) {
        int pn = pblock + (t >> 1);
        if (pn >= NPTS) pn = NPTS - 1;
        int v = t & 1;
        int ii = pn / 1089;
        int rem = pn - ii * 1089;
        int jj = rem / 33;
        int kk = rem - jj * 33;
        float r = kk * (1.0f / 32.0f);
        float g = jj * (1.0f / 32.0f);
        float b = ii * (1.0f / 32.0f);
        float lo = fminf(r, fminf(g, b));
        float hv = fmaxf(r, fmaxf(g, b));
        float mid = r + g + b - lo - hv;    // exact: multiples of 1/32
        Is[t][0] = f2bf(r); Is[t][1] = f2bf(g); Is[t][2] = f2bf(b);
        #pragma unroll
        for (int q = 0; q < 5; ++q)
            Is[t][3 + q] = (v == 0) ? f2bf(param[q]) : (short)0;
        Is[t][8] = f2bf(lo); Is[t][9] = f2bf(mid); Is[t][10] = f2bf(hv);
        #pragma unroll
        for (int q = 11; q < 40; ++q) Is[t][q] = (short)0;
    }
    __syncthreads();

    f32x4 acc[4][4];

    // ---- layer 0: (K=32 padded) -> 256, relu ----
    {
        #pragma unroll
        for (int c = 0; c < 4; ++c) {
            float bv = b0[wid * 64 + c * 16 + lr];
            f32x4 in = {bv, bv, bv, bv};
            #pragma unroll
            for (int rt = 0; rt < 4; ++rt) acc[rt][c] = in;
        }
        short8 a[4], bfr[4];
        #pragma unroll
        for (int rt = 0; rt < 4; ++rt) a[rt] = *(const short8*)&Is[rt * 16 + lr][k8];
        #pragma unroll
        for (int c = 0; c < 4; ++c)
            bfr[c] = *(const short8*)(P + ((long)(wid * 4 + c) * 64 + lane) * 8);
        #pragma unroll
        for (int rt = 0; rt < 4; ++rt)
            #pragma unroll
            for (int c = 0; c < 4; ++c)
                acc[rt][c] = __builtin_amdgcn_mfma_f32_16x16x32_bf16(a[rt], bfr[c], acc[rt][c], 0, 0, 0);
        #pragma unroll
        for (int rt = 0; rt < 4; ++rt)
            #pragma unroll
            for (int c = 0; c < 4; ++c)
                #pragma unroll
                for (int q = 0; q < 4; ++q)
                    Hs[rt * 16 + hi * 4 + q][wid * 64 + c * 16 + lr] = f2bf(fmaxf(acc[rt][c][q], 0.0f));
    }
    __syncthreads();

    // ---- layers 1..3: 256 -> 256, tanh ----
    const long loff[3] = {W1P_OFF, W2P_OFF, W3P_OFF};
    const float* bptr[3];
    bptr[0] = b1; bptr[1] = b2; bptr[2] = b3;
    for (int L = 0; L < 3; ++L) {
        const short* WL = P + loff[L];
        const float* bb = bptr[L];
        #pragma unroll
        for (int c = 0; c < 4; ++c) {
            float bv = bb[wid * 64 + c * 16 + lr];
            f32x4 in = {bv, bv, bv, bv};
            #pragma unroll
            for (int rt = 0; rt < 4; ++rt) acc[rt][c] = in;
        }
        #pragma unroll
        for (int kt = 0; kt < 8; ++kt) {
            short8 a[4], bfr[4];
            #pragma unroll
            for (int rt = 0; rt < 4; ++rt)
                a[rt] = *(const short8*)&Hs[rt * 16 + lr][kt * 32 + k8];
            #pragma unroll
            for (int c = 0; c < 4; ++c)
                bfr[c] = *(const short8*)(WL + ((long)(kt * 16 + wid * 4 + c) * 64 + lane) * 8);
            #pragma unroll
            for (int rt = 0; rt < 4; ++rt)
                #pragma unroll
                for (int c = 0; c < 4; ++c)
                    acc[rt][c] = __builtin_amdgcn_mfma_f32_16x16x32_bf16(a[rt], bfr[c], acc[rt][c], 0, 0, 0);
        }
        __syncthreads();
        #pragma unroll
        for (int rt = 0; rt < 4; ++rt)
            #pragma unroll
            for (int c = 0; c < 4; ++c)
                #pragma unroll
                for (int q = 0; q < 4; ++q)
                    Hs[rt * 16 + hi * 4 + q][wid * 64 + c * 16 + lr] = f2bf(fast_tanh(acc[rt][c][q]));
        __syncthreads();
    }

    // ---- layer 4: 256 -> 3 (N padded to 16); wave wid owns row-tile wid ----
    {
        float bv = (lr < 3) ? b4[lr] : 0.0f;
        f32x4 a4 = {bv, bv, bv, bv};
        const short* WL = P + W4P_OFF;
        #pragma unroll
        for (int kt = 0; kt < 8; ++kt) {
            short8 a = *(const short8*)&Hs[wid * 16 + lr][kt * 32 + k8];
            short8 b = *(const short8*)(WL + ((long)kt * 64 + lane) * 8);
            a4 = __builtin_amdgcn_mfma_f32_16x16x32_bf16(a, b, a4, 0, 0, 0);
        }
        if (lr < 3) {
            #pragma unroll
            for (int q = 0; q < 4; ++q)
                OB[wid * 16 + hi * 4 + q][lr] = a4[q];
        }
    }
    __syncthreads();

    if (t < 96) {
        int pl = t / 3, c = t - pl * 3;
        int n = pblock + pl;
        if (n < NPTS) {
            int ii = n / 1089;
            int rem = n - ii * 1089;
            int jj = rem / 33;
            int kk = rem - jj * 33;
            float rgb = (c == 0) ? kk * (1.0f / 32.0f)
                      : (c == 1) ? jj * (1.0f / 32.0f)
                                 : ii * (1.0f / 32.0f);
            lut4[n * 4 + c] = OB[2 * pl][c] - OB[2 * pl + 1][c] + rgb;
        }
    }
}

// ---------- cell expansion: 32^3 cells, 8 corners each, fp16x4 per corner ----------
// cell (ib,ig,ir) -> cells[cell*32 .. +32) halves; corner (db,dg,dr) at offset (db*4+dg*2+dr)*4
__global__ __launch_bounds__(256) void expand_cells_kernel(
    const float* __restrict__ lut4, __half* __restrict__ cells)
{
    int id = blockIdx.x * 256 + threadIdx.x;     // cell*8 + corner
    if (id >= 32768 * 8) return;
    int corner = id & 7;
    int cell   = id >> 3;
    int ir = cell & 31, ig = (cell >> 5) & 31, ib = cell >> 10;
    int dr = corner & 1, dg = (corner >> 1) & 1, db = (corner >> 2) & 1;
    int src = (ib + db) * 1089 + (ig + dg) * 33 + (ir + dr);
    float4 v = *(const float4*)(lut4 + (long)src * 4);
    union { __half h[4]; uint2 u; } pk;
    pk.h[0] = __float2half_rn(v.x);
    pk.h[1] = __float2half_rn(v.y);
    pk.h[2] = __float2half_rn(v.z);
    pk.h[3] = __float2half_rn(0.0f);
    *(uint2*)(cells + (long)cell * 32 + corner * 4) = pk.u;
}

// ---------- trilinear apply from duplicated cells ----------
#define LERP(a, b, f) fmaf((f), (b) - (a), (a))

__global__ __launch_bounds__(256) void apply_lut_kernel(
    const float* __restrict__ img, const __half* __restrict__ cells,
    float* __restrict__ out)
{
    const int NP = 2160 * 3840;
    int idx = blockIdx.x * blockDim.x + threadIdx.x;
    int p = idx * 4;
    if (p >= NP) return;

    float4 rv = *(const float4*)(img + p);
    float4 gv = *(const float4*)(img + NP + p);
    float4 bv = *(const float4*)(img + 2 * NP + p);

    float rr[4] = {rv.x, rv.y, rv.z, rv.w};
    float gg[4] = {gv.x, gv.y, gv.z, gv.w};
    float bb[4] = {bv.x, bv.y, bv.z, bv.w};
    float ox[4], oy[4], oz[4];

    #pragma unroll
    for (int u = 0; u < 4; ++u) {
        float sr = rr[u] * 32.0f, sg = gg[u] * 32.0f, sb = bb[u] * 32.0f;
        float fir = fminf(fmaxf(floorf(sr), 0.0f), 31.0f);
        float fig = fminf(fmaxf(floorf(sg), 0.0f), 31.0f);
        float fib = fminf(fmaxf(floorf(sb), 0.0f), 31.0f);
        float fr = sr - fir, fg = sg - fig, fb = sb - fib;
        int ir = (int)fir, ig = (int)fig, ib = (int)fib;

        const short8* cb = (const short8*)(cells + ((long)(ib * 1024 + ig * 32 + ir)) * 32);
        union { short8 s; __half h[8]; } u0, u1, u2, u3;
        u0.s = cb[0];   // corners (0,0,0),(0,0,1)
        u1.s = cb[1];   // corners (0,1,0),(0,1,1)
        u2.s = cb[2];   // corners (1,0,0),(1,0,1)
        u3.s = cb[3];   // corners (1,1,0),(1,1,1)

        float v00[3], v01[3], v10[3], v11[3];
        #pragma unroll
        for (int c = 0; c < 3; ++c) {
            v00[c] = LERP(__half2float(u0.h[c]), __half2float(u0.h[c + 4]), fr);
            v01[c] = LERP(__half2float(u1.h[c]), __half2float(u1.h[c + 4]), fr);
            v10[c] = LERP(__half2float(u2.h[c]), __half2float(u2.h[c + 4]), fr);
            v11[c] = LERP(__half2float(u3.h[c]), __half2float(u3.h[c + 4]), fr);
        }
        ox[u] = LERP(LERP(v00[0], v01[0], fg), LERP(v10[0], v11[0], fg), fb);
        oy[u] = LERP(LERP(v00[1], v01[1], fg), LERP(v10[1], v11[1], fg), fb);
        oz[u] = LERP(LERP(v00[2], v01[2], fg), LERP(v10[2], v11[2], fg), fb);
    }

    *(float4*)(out + p)          = make_float4(ox[0], ox[1], ox[2], ox[3]);
    *(float4*)(out + NP + p)     = make_float4(oy[0], oy[1], oy[2], oy[3]);
    *(float4*)(out + 2 * NP + p) = make_float4(oz[0], oz[1], oz[2], oz[3]);
}

extern "C" void kernel_launch(void* const* d_in, const int* in_sizes, int n_in,
                              void* d_out, int out_size, void* d_ws, size_t ws_size,
                              hipStream_t stream) {
    const float* img   = (const float*)d_in[0];
    const float* param = (const float*)d_in[1];
    const float* W0 = (const float*)d_in[2];
    const float* b0 = (const float*)d_in[3];
    const float* W1 = (const float*)d_in[4];
    const float* b1 = (const float*)d_in[5];
    const float* W2 = (const float*)d_in[6];
    const float* b2 = (const float*)d_in[7];
    const float* W3 = (const float*)d_in[8];
    const float* b3 = (const float*)d_in[9];
    const float* W4 = (const float*)d_in[10];
    const float* b4 = (const float*)d_in[11];

    short*  P     = (short*)d_ws;
    float*  lut4  = (float*)((char*)d_ws + LUT_BYTE_OFF);
    __half* cells = (__half*)((char*)d_ws + CELL_BYTE_OFF);
    float*  out   = (float*)d_out;

    hipLaunchKernelGGL(pack_weights_kernel, dim3(102), dim3(TPB), 0, stream,
                       W0, W1, W2, W3, W4, P);

    int lut_blocks = (NPTS + 31) / 32;     // 1124
    hipLaunchKernelGGL(nilut_mfma_kernel, dim3(lut_blocks), dim3(TPB), 0, stream,
                       param, P, b0, b1, b2, b3, b4, lut4);

    hipLaunchKernelGGL(expand_cells_kernel, dim3(1024), dim3(TPB), 0, stream,
                       lut4, cells);

    const int NP = 2160 * 3840;
    int apply_blocks = (NP / 4 + TPB - 1) / TPB;   // 8100
    hipLaunchKernelGGL(apply_lut_kernel, dim3(apply_blocks), dim3(TPB), 0, stream,
                       img, cells, out);
}